// Round 1
// baseline (33606.659 us; speedup 1.0000x reference)
//
#include <hip/hip_runtime.h>

#define NB 64
#define NT 512
#define NIN 1024
#define NH 1024
#define NWG 128

typedef _Float16 half8 __attribute__((ext_vector_type(8)));
typedef float floatx4 __attribute__((ext_vector_type(4)));

union HV8 { _Float16 h[8]; uint4 u; };

// ws layout
#define WFRAG_OFF 0u
#define WFRAG_BYTES (128u*5u*32u*64u*8u*2u)          // 20971520
#define WHT_OFF   (WFRAG_OFF + WFRAG_BYTES)          // 20971520
#define WHT_BYTES (2048u*1024u*2u)                   // 4194304
#define S16A_OFF  (WHT_OFF + WHT_BYTES)              // 25165824
#define S16_BYTES (NB*NH*2u)                         // 131072
#define S16B_OFF  (S16A_OFF + S16_BYTES)
#define BAR_OFF   (S16B_OFF + S16_BYTES)

// --------------------------------------------------------------------------
// Prep 0: recurrent weights -> fp16 fragments, laid out so each wave's slice
// is a contiguous run of 16B chunks: frag id = ((wg*5+l)*32+ks)*64+lane.
// B-frag element j of lane: W[gate][g = wg*8 + (n&7)][k = ks*32 + q*8 + j],
// n = lane&15 (n>=8 -> t-gate), q = lane>>4.
__global__ __launch_bounds__(256) void prep_wfrag(
    const float* __restrict__ rh_w, const float* __restrict__ rt_w,
    _Float16* __restrict__ wfrag)
{
  int id = blockIdx.x * 256 + threadIdx.x;   // 0 .. 128*5*32*64
  int lane = id & 63;
  int ks = (id >> 6) & 31;
  int wl = id >> 11;            // wg*5 + l
  int l = wl % 5;
  int wg = wl / 5;
  int n = lane & 15, q = lane >> 4;
  int gate = n >> 3;
  int g = wg * 8 + (n & 7);
  int k0 = ks * 32 + q * 8;
  const float* src = (gate ? rt_w : rh_w) + ((size_t)l * NH + g) * NH + k0;
  float4 f0 = ((const float4*)src)[0];
  float4 f1 = ((const float4*)src)[1];
  HV8 t;
  t.h[0] = (_Float16)f0.x; t.h[1] = (_Float16)f0.y;
  t.h[2] = (_Float16)f0.z; t.h[3] = (_Float16)f0.w;
  t.h[4] = (_Float16)f1.x; t.h[5] = (_Float16)f1.y;
  t.h[6] = (_Float16)f1.z; t.h[7] = (_Float16)f1.w;
  *(uint4*)(wfrag + (size_t)id * 8) = t.u;
}

// --------------------------------------------------------------------------
// Prep 1: w_h/w_t [IN][H] fp32 -> whT [2048][1024] fp16 (row n: n<1024 = w_h
// column n, n>=1024 = w_t column n-1024). Also init s16a from s (zeros) and
// zero the barrier counter. id = kc*2048 + nn so source reads are coalesced.
__global__ __launch_bounds__(256) void prep_misc(
    const float* __restrict__ w_h, const float* __restrict__ w_t,
    const float* __restrict__ s_in,
    _Float16* __restrict__ whT, _Float16* __restrict__ s16a,
    unsigned* __restrict__ bar)
{
  int id = blockIdx.x * 256 + threadIdx.x;   // 0 .. 128*2048
  int nn = id & 2047;
  int kc = id >> 11;                          // 0..127
  int gate = nn >> 10, g = nn & 1023;
  const float* src = gate ? w_t : w_h;
  HV8 t;
#pragma unroll
  for (int j = 0; j < 8; j++) t.h[j] = (_Float16)src[(size_t)(kc * 8 + j) * NH + g];
  *(uint4*)(whT + (size_t)nn * NIN + kc * 8) = t.u;
  if (id < NB * NH) s16a[id] = (_Float16)s_in[id];
  if (id == 0) bar[0] = 0u;
}

// --------------------------------------------------------------------------
// Phase 1: WHX/WTX = x @ [w_h | w_t]  (M=32768, N=2048, K=1024), fp16 MFMA.
// Output packed as fp16 pairs into the fp32 out buffer:
//   outH[((row*1024+g)*2 + gate)] , row = b*T + t.
__global__ __launch_bounds__(256) void gemm_in(
    const float* __restrict__ x, const _Float16* __restrict__ whT,
    _Float16* outH)
{
  __shared__ __align__(16) _Float16 aS[8][64][8];
  __shared__ __align__(16) _Float16 bS[8][64][8];
  int tid = threadIdx.x, lane = tid & 63, w = tid >> 6;
  int m0 = blockIdx.x * 128, n0 = blockIdx.y * 128;
  int srow = tid >> 1, shf = tid & 1;
  int q = lane >> 4, nl = lane & 15;
  floatx4 acc[4][4] = {};
  const float*    ap = x   + (size_t)(m0 + srow) * NIN + shf * 16;
  const _Float16* bp = whT + (size_t)(n0 + srow) * NIN + shf * 16;
  int la = ((shf * 2)     << 4) | (srow & 15);
  int lb = ((shf * 2 + 1) << 4) | (srow & 15);
  int smt = srow >> 4;
  for (int kc = 0; kc < 32; kc++) {
    float4 f0 = ((const float4*)ap)[0];
    float4 f1 = ((const float4*)ap)[1];
    float4 f2 = ((const float4*)ap)[2];
    float4 f3 = ((const float4*)ap)[3];
    HV8 ua, ub;
    ua.h[0]=(_Float16)f0.x; ua.h[1]=(_Float16)f0.y; ua.h[2]=(_Float16)f0.z; ua.h[3]=(_Float16)f0.w;
    ua.h[4]=(_Float16)f1.x; ua.h[5]=(_Float16)f1.y; ua.h[6]=(_Float16)f1.z; ua.h[7]=(_Float16)f1.w;
    ub.h[0]=(_Float16)f2.x; ub.h[1]=(_Float16)f2.y; ub.h[2]=(_Float16)f2.z; ub.h[3]=(_Float16)f2.w;
    ub.h[4]=(_Float16)f3.x; ub.h[5]=(_Float16)f3.y; ub.h[6]=(_Float16)f3.z; ub.h[7]=(_Float16)f3.w;
    uint4 b0 = ((const uint4*)bp)[0];
    uint4 b1 = ((const uint4*)bp)[1];
    *(uint4*)&aS[smt][la][0] = ua.u;
    *(uint4*)&aS[smt][lb][0] = ub.u;
    *(uint4*)&bS[smt][la][0] = b0;
    *(uint4*)&bS[smt][lb][0] = b1;
    __syncthreads();
    half8 af[4], bf[4];
#pragma unroll
    for (int mt = 0; mt < 4; mt++) af[mt] = *(const half8*)&aS[(w >> 1) * 4 + mt][lane][0];
#pragma unroll
    for (int nt = 0; nt < 4; nt++) bf[nt] = *(const half8*)&bS[(w & 1) * 4 + nt][lane][0];
#pragma unroll
    for (int mt = 0; mt < 4; mt++)
#pragma unroll
      for (int nt = 0; nt < 4; nt++)
        acc[mt][nt] = __builtin_amdgcn_mfma_f32_16x16x32_f16(af[mt], bf[nt], acc[mt][nt], 0, 0, 0);
    __syncthreads();
    ap += 32; bp += 32;
  }
#pragma unroll
  for (int mt = 0; mt < 4; mt++)
#pragma unroll
    for (int nt = 0; nt < 4; nt++) {
      int nG = n0 + (w & 1) * 64 + nt * 16 + nl;
      int gate = nG >> 10, g = nG & 1023;
#pragma unroll
      for (int i = 0; i < 4; i++) {
        int row = m0 + (w >> 1) * 64 + mt * 16 + q * 4 + i;
        outH[((size_t)row * NH + g) * 2 + gate] = (_Float16)acc[mt][nt][i];
      }
    }
}

// --------------------------------------------------------------------------
// Persistent recurrence. 128 WGs x 256 threads, all co-resident.
// WG wg owns g-slice [wg*8, wg*8+8), MFMA N=16 = 8g x 2 gates.
// Weights: register-resident (wave w holds ksteps w*8..w*8+7, all 5 layers).
// K-reduction across the 4 waves via 16 KB LDS; wave w finishes M-tile w.
// s: fp16 ping-pong buffers in ws. Grid barrier: monotonic atomic counter.
__global__ __launch_bounds__(256, 1) void rhn_rec(
    const _Float16* __restrict__ wfrag,
    _Float16* s16a, _Float16* s16b,
    const float* __restrict__ s_in,
    const float* __restrict__ rh_b, const float* __restrict__ rt_b,
    float* out, unsigned* bar)
{
  __shared__ floatx4 red[4][4][64];
  int wg = blockIdx.x;
  int tid = threadIdx.x, lane = tid & 63, w = tid >> 6;
  int n = lane & 15, q = lane >> 4;
  int gate = n >> 3;
  int g = wg * 8 + (n & 7);
  _Float16* outH = (_Float16*)out;

  // register-resident weight fragments: 5 layers x 8 local ksteps
  half8 W[5][8];
#pragma unroll
  for (int l = 0; l < 5; l++)
#pragma unroll
    for (int ks = 0; ks < 8; ks++)
      W[l][ks] = *(const half8*)(wfrag +
          ((((size_t)wg * 5 + l) * 32 + (w * 8 + ks)) * 64 + lane) * 8);

  float bias[5];
#pragma unroll
  for (int l = 0; l < 5; l++) bias[l] = (gate ? rt_b : rh_b)[l * NH + g];

  // wave w's epilogue owns rows b = w*16 + q*4 + i (lanes n<8 hold state)
  float sold[4];
#pragma unroll
  for (int i = 0; i < 4; i++)
    sold[i] = s_in[(size_t)(w * 16 + q * 4 + i) * NH + g];

  const _Float16* sRead = s16a;
  _Float16* sWrite = s16b;
  unsigned stage = 0;

#pragma unroll 1
  for (int t = 0; t < NT; t++) {
#pragma unroll
    for (int l = 0; l < 5; l++) {
      // prefetch whx/wtx (packed fp16 in out) for layer 0
      float wxv[4] = {0.f, 0.f, 0.f, 0.f};
      if (l == 0) {
#pragma unroll
        for (int i = 0; i < 4; i++) {
          size_t b = (size_t)(w * 16 + q * 4 + i);
          wxv[i] = (float)outH[((b * NT + t) * NH + g) * 2 + gate];
        }
      }
      // matmul: partial K (this wave's 8 ksteps) over 4 M-tiles
      floatx4 acc[4] = {};
      uint4 abuf[2][4];
#pragma unroll
      for (int mt = 0; mt < 4; mt++)
        abuf[0][mt] = *(const uint4*)(sRead + (size_t)(mt * 16 + n) * NH + (w * 8 + 0) * 32 + q * 8);
#pragma unroll
      for (int ks = 0; ks < 8; ks++) {
        if (ks < 7) {
#pragma unroll
          for (int mt = 0; mt < 4; mt++)
            abuf[(ks + 1) & 1][mt] =
                *(const uint4*)(sRead + (size_t)(mt * 16 + n) * NH + (w * 8 + ks + 1) * 32 + q * 8);
        }
#pragma unroll
        for (int mt = 0; mt < 4; mt++)
          acc[mt] = __builtin_amdgcn_mfma_f32_16x16x32_f16(
              __builtin_bit_cast(half8, abuf[ks & 1][mt]), W[l][ks], acc[mt], 0, 0, 0);
      }
      // cross-wave K reduction
#pragma unroll
      for (int mt = 0; mt < 4; mt++) red[w][mt][lane] = acc[mt];
      __syncthreads();
      floatx4 pre = red[0][w][lane] + red[1][w][lane] + red[2][w][lane] + red[3][w][lane];
      // activations: tanh(x) = 2*sigmoid(2x)-1 (one exp, no lane divergence)
      float act[4];
#pragma unroll
      for (int i = 0; i < 4; i++) {
        float xv = pre[i] + bias[l];
        if (l == 0) xv += wxv[i];
        float y = gate ? xv : 2.f * xv;
        float sg = 1.f / (1.f + __expf(-y));
        act[i] = gate ? sg : (2.f * sg - 1.f);
      }
      // highway blend: lanes n<8 (h-role) fetch partner sigmoid via lane^8
#pragma unroll
      for (int i = 0; i < 4; i++) {
        float tp = __shfl(act[i], lane ^ 8, 64);
        float sn = (act[i] - sold[i]) * tp + sold[i];
        if (n < 8) sold[i] = sn;
      }
      if (n < 8) {
#pragma unroll
        for (int i = 0; i < 4; i++) {
          size_t b = (size_t)(w * 16 + q * 4 + i);
          sWrite[b * NH + g] = (_Float16)sold[i];
          if (l == 4) {
            out[(b * NT + t) * NH + g] = sold[i];
            if (t == NT - 1) out[(size_t)NB * NT * NH + b * NH + g] = sold[i];
          }
        }
      }
      // swap ping-pong state buffers
      {
        const _Float16* tr = sRead;
        sRead = sWrite;
        sWrite = (_Float16*)tr;
      }
      // grid barrier (monotonic counter, device scope)
      stage++;
      __syncthreads();
      if (tid == 0) {
        __threadfence();
        atomicAdd(bar, 1u);
        unsigned target = stage * NWG;
        while (__hip_atomic_load(bar, __ATOMIC_RELAXED, __HIP_MEMORY_SCOPE_AGENT) < target)
          __builtin_amdgcn_s_sleep(2);
        __threadfence();
      }
      __syncthreads();
    }
  }
}

// --------------------------------------------------------------------------
extern "C" void kernel_launch(void* const* d_in, const int* in_sizes, int n_in,
                              void* d_out, int out_size, void* d_ws, size_t ws_size,
                              hipStream_t stream)
{
  (void)in_sizes; (void)n_in; (void)out_size; (void)ws_size;
  const float* x    = (const float*)d_in[0];
  const float* s_in = (const float*)d_in[1];
  const float* w_h  = (const float*)d_in[2];
  const float* w_t  = (const float*)d_in[3];
  const float* rh_w = (const float*)d_in[4];
  const float* rh_b = (const float*)d_in[5];
  const float* rt_w = (const float*)d_in[6];
  const float* rt_b = (const float*)d_in[7];
  float* out = (float*)d_out;
  char* ws = (char*)d_ws;
  _Float16* wfrag = (_Float16*)(ws + WFRAG_OFF);
  _Float16* whT   = (_Float16*)(ws + WHT_OFF);
  _Float16* s16a  = (_Float16*)(ws + S16A_OFF);
  _Float16* s16b  = (_Float16*)(ws + S16B_OFF);
  unsigned* bar   = (unsigned*)(ws + BAR_OFF);

  hipLaunchKernelGGL(prep_wfrag, dim3(5120), dim3(256), 0, stream, rh_w, rt_w, wfrag);
  hipLaunchKernelGGL(prep_misc,  dim3(1024), dim3(256), 0, stream, w_h, w_t, s_in, whT, s16a, bar);
  hipLaunchKernelGGL(gemm_in,    dim3(256, 16), dim3(256), 0, stream, x, whT, (_Float16*)out);
  hipLaunchKernelGGL(rhn_rec,    dim3(NWG), dim3(256), 0, stream, wfrag, s16a, s16b, s_in, rh_b, rt_b, out, bar);
}

// Round 2
// 25535.402 us; speedup vs baseline: 1.3161x; 1.3161x over previous
//
#include <hip/hip_runtime.h>

#define NB 64
#define NT 512
#define NIN 1024
#define NH 1024
#define NWG 128

typedef _Float16 half8 __attribute__((ext_vector_type(8)));
typedef _Float16 half4 __attribute__((ext_vector_type(4)));
typedef float floatx4 __attribute__((ext_vector_type(4)));

union HV8 { _Float16 h[8]; uint4 u; };
union HV4 { _Float16 h[4]; uint2 u2; unsigned u[2]; };

// ws layout
#define WFRAG_OFF 0u
#define WFRAG_BYTES (128u*5u*32u*64u*8u*2u)          // 20971520
#define WHT_OFF   (WFRAG_OFF + WFRAG_BYTES)          // 20971520
#define WHT_BYTES (2048u*1024u*2u)                   // 4194304
#define S16A_OFF  (WHT_OFF + WHT_BYTES)              // 25165824
#define S16_BYTES (NB*NH*2u)                         // 131072
#define S16B_OFF  (S16A_OFF + S16_BYTES)
#define ARR_OFF   (S16B_OFF + S16_BYTES)             // 8 counters, 256B apart
#define REL_OFF   (ARR_OFF + 4096u)

// --------------------------------------------------------------------------
// Prep 0: recurrent weights -> fp16 A-operand fragments.
// frag id = ((wg*5+l)*32+ks)*64+lane; lane: m = lane&15 (m>=8 -> t-gate),
// q = lane>>4; element j: W[gate][g = wg*8 + (m&7)][k = ks*32 + q*8 + j].
__global__ __launch_bounds__(256) void prep_wfrag(
    const float* __restrict__ rh_w, const float* __restrict__ rt_w,
    _Float16* __restrict__ wfrag)
{
  int id = blockIdx.x * 256 + threadIdx.x;   // 0 .. 128*5*32*64
  int lane = id & 63;
  int ks = (id >> 6) & 31;
  int wl = id >> 11;            // wg*5 + l
  int l = wl % 5;
  int wg = wl / 5;
  int m = lane & 15, q = lane >> 4;
  int gate = m >> 3;
  int g = wg * 8 + (m & 7);
  int k0 = ks * 32 + q * 8;
  const float* src = (gate ? rt_w : rh_w) + ((size_t)l * NH + g) * NH + k0;
  float4 f0 = ((const float4*)src)[0];
  float4 f1 = ((const float4*)src)[1];
  HV8 t;
  t.h[0] = (_Float16)f0.x; t.h[1] = (_Float16)f0.y;
  t.h[2] = (_Float16)f0.z; t.h[3] = (_Float16)f0.w;
  t.h[4] = (_Float16)f1.x; t.h[5] = (_Float16)f1.y;
  t.h[6] = (_Float16)f1.z; t.h[7] = (_Float16)f1.w;
  *(uint4*)(wfrag + (size_t)id * 8) = t.u;
}

// --------------------------------------------------------------------------
// Prep 1: w_h/w_t [IN][H] fp32 -> whT [2048][1024] fp16. Also init s16a and
// the barrier counters/release word.
__global__ __launch_bounds__(256) void prep_misc(
    const float* __restrict__ w_h, const float* __restrict__ w_t,
    const float* __restrict__ s_in,
    _Float16* __restrict__ whT, _Float16* __restrict__ s16a,
    unsigned* __restrict__ arr, unsigned* __restrict__ rel)
{
  int id = blockIdx.x * 256 + threadIdx.x;   // 0 .. 128*2048
  int nn = id & 2047;
  int kc = id >> 11;                          // 0..127
  int gate = nn >> 10, g = nn & 1023;
  const float* src = gate ? w_t : w_h;
  HV8 t;
#pragma unroll
  for (int j = 0; j < 8; j++) t.h[j] = (_Float16)src[(size_t)(kc * 8 + j) * NH + g];
  *(uint4*)(whT + (size_t)nn * NIN + kc * 8) = t.u;
  if (id < NB * NH) s16a[id] = (_Float16)s_in[id];
  if (id < 8) arr[id * 64] = 0u;
  if (id == 8) rel[0] = 0u;
}

// --------------------------------------------------------------------------
// Phase 1: WHX/WTX = x @ [w_h | w_t]  (M=32768, N=2048, K=1024), fp16 MFMA.
// Output packed fp16: outH[row*2048 + gate*1024 + g], row = b*T + t.
__global__ __launch_bounds__(256) void gemm_in(
    const float* __restrict__ x, const _Float16* __restrict__ whT,
    _Float16* outH)
{
  __shared__ __align__(16) _Float16 aS[8][64][8];
  __shared__ __align__(16) _Float16 bS[8][64][8];
  int tid = threadIdx.x, lane = tid & 63, w = tid >> 6;
  int m0 = blockIdx.x * 128, n0 = blockIdx.y * 128;
  int srow = tid >> 1, shf = tid & 1;
  int q = lane >> 4, nl = lane & 15;
  floatx4 acc[4][4] = {};
  const float*    ap = x   + (size_t)(m0 + srow) * NIN + shf * 16;
  const _Float16* bp = whT + (size_t)(n0 + srow) * NIN + shf * 16;
  int la = ((shf * 2)     << 4) | (srow & 15);
  int lb = ((shf * 2 + 1) << 4) | (srow & 15);
  int smt = srow >> 4;
  for (int kc = 0; kc < 32; kc++) {
    float4 f0 = ((const float4*)ap)[0];
    float4 f1 = ((const float4*)ap)[1];
    float4 f2 = ((const float4*)ap)[2];
    float4 f3 = ((const float4*)ap)[3];
    HV8 ua, ub;
    ua.h[0]=(_Float16)f0.x; ua.h[1]=(_Float16)f0.y; ua.h[2]=(_Float16)f0.z; ua.h[3]=(_Float16)f0.w;
    ua.h[4]=(_Float16)f1.x; ua.h[5]=(_Float16)f1.y; ua.h[6]=(_Float16)f1.z; ua.h[7]=(_Float16)f1.w;
    ub.h[0]=(_Float16)f2.x; ub.h[1]=(_Float16)f2.y; ub.h[2]=(_Float16)f2.z; ub.h[3]=(_Float16)f2.w;
    ub.h[4]=(_Float16)f3.x; ub.h[5]=(_Float16)f3.y; ub.h[6]=(_Float16)f3.z; ub.h[7]=(_Float16)f3.w;
    uint4 b0 = ((const uint4*)bp)[0];
    uint4 b1 = ((const uint4*)bp)[1];
    *(uint4*)&aS[smt][la][0] = ua.u;
    *(uint4*)&aS[smt][lb][0] = ub.u;
    *(uint4*)&bS[smt][la][0] = b0;
    *(uint4*)&bS[smt][lb][0] = b1;
    __syncthreads();
    half8 af[4], bf[4];
#pragma unroll
    for (int mt = 0; mt < 4; mt++) af[mt] = *(const half8*)&aS[(w >> 1) * 4 + mt][lane][0];
#pragma unroll
    for (int nt = 0; nt < 4; nt++) bf[nt] = *(const half8*)&bS[(w & 1) * 4 + nt][lane][0];
#pragma unroll
    for (int mt = 0; mt < 4; mt++)
#pragma unroll
      for (int nt = 0; nt < 4; nt++)
        acc[mt][nt] = __builtin_amdgcn_mfma_f32_16x16x32_f16(af[mt], bf[nt], acc[mt][nt], 0, 0, 0);
    __syncthreads();
    ap += 32; bp += 32;
  }
#pragma unroll
  for (int mt = 0; mt < 4; mt++)
#pragma unroll
    for (int nt = 0; nt < 4; nt++) {
      int nG = n0 + (w & 1) * 64 + nt * 16 + nl;
      int gate = nG >> 10, g = nG & 1023;
#pragma unroll
      for (int i = 0; i < 4; i++) {
        int row = m0 + (w >> 1) * 64 + mt * 16 + q * 4 + i;
        outH[(size_t)row * 2048 + gate * 1024 + g] = (_Float16)acc[mt][nt][i];
      }
    }
}

// --------------------------------------------------------------------------
// Persistent recurrence. 128 WGs x 256 threads, all co-resident.
// MFMA role-swap: A = W (register-resident), B = s fragments, so
// D[m = gate*8+gc][n = batch]. Epilogue lane (n,q): batch b = w*16+n,
// gate = q>>1, g = wg*8+(q&1)*4 + i (4 consecutive columns).
// s exchange: agent-scope relaxed atomic stores (write-through, no dirty L2)
// + hierarchical arrival counters + broadcast release + acquire fence.
__global__ __launch_bounds__(256, 1) void rhn_rec(
    const _Float16* __restrict__ wfrag,
    _Float16* s16a, _Float16* s16b,
    const float* __restrict__ s_in,
    const float* __restrict__ rh_b, const float* __restrict__ rt_b,
    float* out, unsigned* arr, unsigned* rel)
{
  __shared__ floatx4 red[4][4][64];
  int wg = blockIdx.x;
  int tid = threadIdx.x, lane = tid & 63, w = tid >> 6;
  int n = lane & 15, q = lane >> 4;
  int gate = q >> 1;                  // epilogue: which gate this lane's rows are
  int g0 = wg * 8 + (q & 1) * 4;      // epilogue: 4 consecutive g columns
  int b = w * 16 + n;                 // epilogue: this lane's batch row
  _Float16* outH = (_Float16*)out;

  // register-resident weight fragments: 5 layers x 8 local ksteps
  half8 W[5][8];
#pragma unroll
  for (int l = 0; l < 5; l++)
#pragma unroll
    for (int ks = 0; ks < 8; ks++)
      W[l][ks] = *(const half8*)(wfrag +
          ((((size_t)wg * 5 + l) * 32 + (w * 8 + ks)) * 64 + lane) * 8);

  float bias4[5][4];
#pragma unroll
  for (int l = 0; l < 5; l++)
#pragma unroll
    for (int i = 0; i < 4; i++)
      bias4[l][i] = (gate ? rt_b : rh_b)[l * NH + g0 + i];

  float sold[4];
#pragma unroll
  for (int i = 0; i < 4; i++)
    sold[i] = s_in[(size_t)b * NH + g0 + i];

  const _Float16* sRead = s16a;
  _Float16* sWrite = s16b;
  unsigned stage = 0;

#pragma unroll 1
  for (int t = 0; t < NT; t++) {
#pragma unroll
    for (int l = 0; l < 5; l++) {
      // wx for layer 0: 4 consecutive fp16 (packed [row][gate][g])
      float wxv[4] = {0.f, 0.f, 0.f, 0.f};
      if (l == 0) {
        HV4 wx;
        wx.u2 = *(const uint2*)(outH + ((size_t)b * NT + t) * 2048 + gate * 1024 + g0);
#pragma unroll
        for (int i = 0; i < 4; i++) wxv[i] = (float)wx.h[i];
      }
      // matmul: this wave's 8 ksteps over 4 batch-tiles (B-operand = s)
      floatx4 acc[4] = {};
      uint4 abuf[2][4];
#pragma unroll
      for (int nt = 0; nt < 4; nt++)
        abuf[0][nt] = *(const uint4*)(sRead + (size_t)(nt * 16 + n) * NH + (w * 8 + 0) * 32 + q * 8);
#pragma unroll
      for (int ks = 0; ks < 8; ks++) {
        if (ks < 7) {
#pragma unroll
          for (int nt = 0; nt < 4; nt++)
            abuf[(ks + 1) & 1][nt] =
                *(const uint4*)(sRead + (size_t)(nt * 16 + n) * NH + (w * 8 + ks + 1) * 32 + q * 8);
        }
#pragma unroll
        for (int nt = 0; nt < 4; nt++)
          acc[nt] = __builtin_amdgcn_mfma_f32_16x16x32_f16(
              W[l][ks], __builtin_bit_cast(half8, abuf[ks & 1][nt]), acc[nt], 0, 0, 0);
      }
      // cross-wave K reduction; wave w takes batch-tile w
#pragma unroll
      for (int nt = 0; nt < 4; nt++) red[w][nt][lane] = acc[nt];
      __syncthreads();
      floatx4 pre = red[0][w][lane] + red[1][w][lane] + red[2][w][lane] + red[3][w][lane];
      // activations: tanh(x) = 2*sigmoid(2x)-1
      float act[4];
#pragma unroll
      for (int i = 0; i < 4; i++) {
        float xv = pre[i] + bias4[l][i];
        if (l == 0) xv += wxv[i];
        float y = gate ? xv : 2.f * xv;
        float sg = 1.f / (1.f + __expf(-y));
        act[i] = gate ? sg : (2.f * sg - 1.f);
      }
      // highway blend: h-lanes (q<2) fetch partner sigmoid from lane+32
      float sn[4];
#pragma unroll
      for (int i = 0; i < 4; i++) {
        float tp = __shfl(act[i], lane ^ 32, 64);
        sn[i] = (act[i] - sold[i]) * tp + sold[i];
      }
      if (q < 2) {
#pragma unroll
        for (int i = 0; i < 4; i++) sold[i] = sn[i];
        HV4 pk;
#pragma unroll
        for (int i = 0; i < 4; i++) pk.h[i] = (_Float16)sold[i];
        unsigned* dstu = (unsigned*)(sWrite + (size_t)b * NH + g0);
        __hip_atomic_store(dstu, pk.u[0], __ATOMIC_RELAXED, __HIP_MEMORY_SCOPE_AGENT);
        __hip_atomic_store(dstu + 1, pk.u[1], __ATOMIC_RELAXED, __HIP_MEMORY_SCOPE_AGENT);
        if (l == 4) {
          float4 o;
          o.x = sold[0]; o.y = sold[1]; o.z = sold[2]; o.w = sold[3];
          *(float4*)(out + ((size_t)b * NT + t) * NH + g0) = o;
          if (t == NT - 1)
            *(float4*)(out + (size_t)NB * NT * NH + (size_t)b * NH + g0) = o;
        }
      }
      // swap ping-pong state buffers
      {
        const _Float16* tr = sRead;
        sRead = sWrite;
        sWrite = (_Float16*)tr;
      }
      // grid barrier: hierarchical arrival (8 spaced counters), broadcast release
      stage++;
      __syncthreads();   // drains vmcnt -> coherent s stores are at the LIC
      if (tid == 0)
        __hip_atomic_fetch_add(&arr[(wg & 7) * 64], 1u,
                               __ATOMIC_RELAXED, __HIP_MEMORY_SCOPE_AGENT);
      if (wg == 0) {
        if (tid < 8) {
          unsigned tgt = stage * 16u;
          while (__hip_atomic_load(&arr[tid * 64],
                                   __ATOMIC_RELAXED, __HIP_MEMORY_SCOPE_AGENT) < tgt)
            __builtin_amdgcn_s_sleep(1);
        }
        if (tid == 0) {
          __builtin_amdgcn_s_waitcnt(0);
          __hip_atomic_store(rel, stage, __ATOMIC_RELAXED, __HIP_MEMORY_SCOPE_AGENT);
        }
      } else {
        if (tid == 0) {
          while (__hip_atomic_load(rel,
                                   __ATOMIC_RELAXED, __HIP_MEMORY_SCOPE_AGENT) < stage)
            __builtin_amdgcn_s_sleep(1);
        }
      }
      __syncthreads();
      __builtin_amdgcn_fence(__ATOMIC_ACQUIRE, "agent");  // buffer_inv: fresh s via plain loads
    }
  }
}

// --------------------------------------------------------------------------
extern "C" void kernel_launch(void* const* d_in, const int* in_sizes, int n_in,
                              void* d_out, int out_size, void* d_ws, size_t ws_size,
                              hipStream_t stream)
{
  (void)in_sizes; (void)n_in; (void)out_size; (void)ws_size;
  const float* x    = (const float*)d_in[0];
  const float* s_in = (const float*)d_in[1];
  const float* w_h  = (const float*)d_in[2];
  const float* w_t  = (const float*)d_in[3];
  const float* rh_w = (const float*)d_in[4];
  const float* rh_b = (const float*)d_in[5];
  const float* rt_w = (const float*)d_in[6];
  const float* rt_b = (const float*)d_in[7];
  float* out = (float*)d_out;
  char* ws = (char*)d_ws;
  _Float16* wfrag = (_Float16*)(ws + WFRAG_OFF);
  _Float16* whT   = (_Float16*)(ws + WHT_OFF);
  _Float16* s16a  = (_Float16*)(ws + S16A_OFF);
  _Float16* s16b  = (_Float16*)(ws + S16B_OFF);
  unsigned* arr   = (unsigned*)(ws + ARR_OFF);
  unsigned* rel   = (unsigned*)(ws + REL_OFF);

  hipLaunchKernelGGL(prep_wfrag, dim3(5120), dim3(256), 0, stream, rh_w, rt_w, wfrag);
  hipLaunchKernelGGL(prep_misc,  dim3(1024), dim3(256), 0, stream, w_h, w_t, s_in, whT, s16a, arr, rel);
  hipLaunchKernelGGL(gemm_in,    dim3(256, 16), dim3(256), 0, stream, x, whT, (_Float16*)out);
  hipLaunchKernelGGL(rhn_rec,    dim3(NWG), dim3(256), 0, stream, wfrag, s16a, s16b, s_in, rh_b, rt_b, out, arr, rel);
}